// Round 1
// 154.961 us; speedup vs baseline: 1.0412x; 1.0412x over previous
//
#include <hip/hip_runtime.h>
#include <hip/hip_bf16.h>
#include <stdint.h>

#define NTOK 65536
#define G 4
#define K 1024
#define C 64
#define GC 256
#define NCHUNK 8
#define KCHUNK 128                   // codes per LDS chunk
#define CHUNK_HALVES (KCHUNK * C)    // 8192 halves = 16 KB
#define R 4                          // 16-row tiles per wave -> 64 rows/wave
#define WAVES 4
#define ROWS_PER_WAVE 64
#define ROWS_PER_BLOCK 256           // 4 waves per block
#define EMB16_BYTES (G * K * C * 2)  // 512 KB in d_ws

typedef _Float16 half8 __attribute__((ext_vector_type(8)));
typedef float floatx4 __attribute__((ext_vector_type(4)));

__device__ __forceinline__ void gload_lds16(const _Float16* g, _Float16* l) {
    __builtin_amdgcn_global_load_lds(
        (const __attribute__((address_space(1))) uint32_t*)g,
        (__attribute__((address_space(3))) uint32_t*)l, 16, 0, 0);
}

// Build negated f16 codebook in d_ws, pre-swizzled into MFMA A-fragment order:
// halves offset = ((g*8+chunk)*8+kt)*1024 + s*512 + lane*8 ; lane = q*16+lr holds
// code = chunk*128+kt*16+lr, halves h = s*32+q*8 .. +8   (negated!)
// Also zeroes the loss accumulator slot (main kernel atomically adds into it).
__global__ __launch_bounds__(256)
void vq_prep(const float* __restrict__ emb, _Float16* __restrict__ emb16,
             float* __restrict__ out) {
    int gid   = blockIdx.x * 256 + threadIdx.x;   // 0..32767
    int lane  = gid & 63;
    int s     = (gid >> 6) & 1;
    int kt    = (gid >> 7) & 7;
    int chunk = (gid >> 10) & 7;
    int g     = gid >> 13;
    int code  = chunk * KCHUNK + kt * 16 + (lane & 15);
    int q     = lane >> 4;
    int h     = s * 32 + q * 8;
    const float* src = emb + ((size_t)(g * K + code)) * C + h;
    floatx4 a = *(const floatx4*)src;
    floatx4 b = *(const floatx4*)(src + 4);
    half8 o;
    o[0] = (_Float16)(-a[0]); o[1] = (_Float16)(-a[1]);
    o[2] = (_Float16)(-a[2]); o[3] = (_Float16)(-a[3]);
    o[4] = (_Float16)(-b[0]); o[5] = (_Float16)(-b[1]);
    o[6] = (_Float16)(-b[2]); o[7] = (_Float16)(-b[3]);
    *(half8*)(emb16 + (size_t)gid * 8) = o;
    if (gid == 0) out[(size_t)NTOK * GC] = 0.0f;   // loss slot
}

__global__ __launch_bounds__(256, 4)
void vq_main(const float* __restrict__ z, const float* __restrict__ emb,
             const _Float16* __restrict__ emb16, float* __restrict__ out) {
    __shared__ alignas(16) _Float16 Ebuf[2][CHUNK_HALVES];
    __shared__ float wl[WAVES];

    const int g    = blockIdx.x & 3;
    const int nb   = blockIdx.x >> 2;
    const int wave = threadIdx.x >> 6;
    const int lane = threadIdx.x & 63;
    const int q    = lane >> 4;
    const int lr   = lane & 15;
    const int n0   = nb * ROWS_PER_BLOCK + wave * ROWS_PER_WAVE;

    const _Float16* esrc = emb16 + (size_t)g * (K * C);

    auto stage = [&](int chunk, int buf) {
        const _Float16* src = esrc + chunk * CHUNK_HALVES;
#pragma unroll
        for (int i = 0; i < 4; ++i) {
            const int seg = wave * 4 + i;                 // 512-half (1 KB) segments
            gload_lds16(src + seg * 512 + lane * 8, &Ebuf[buf][seg * 512]);
        }
    };

    stage(0, 0);

    // z fragments: 4 row-tiles x 2 k-steps, f32 -> f16, held in regs (NOT negated)
    half8 zf[R][2];
#pragma unroll
    for (int r = 0; r < R; ++r) {
        const float* zp = z + (size_t)(n0 + r * 16 + lr) * GC + g * C + q * 8;
#pragma unroll
        for (int s = 0; s < 2; ++s) {
            floatx4 a = *(const floatx4*)(zp + s * 32);
            floatx4 b = *(const floatx4*)(zp + s * 32 + 4);
            half8 h;
            h[0] = (_Float16)a[0]; h[1] = (_Float16)a[1];
            h[2] = (_Float16)a[2]; h[3] = (_Float16)a[3];
            h[4] = (_Float16)b[0]; h[5] = (_Float16)b[1];
            h[6] = (_Float16)b[2]; h[7] = (_Float16)b[3];
            zf[r][s] = h;
        }
    }

    // packed argmin state: score' = 0.5 - z.e (always positive), low 10 bits = code id
    float best[R];
#pragma unroll
    for (int r = 0; r < R; ++r) best[r] = 3.4e38f;
    int vki[4];
#pragma unroll
    for (int j = 0; j < 4; ++j) vki[j] = q * 4 + j;

    const floatx4 BIAS = {0.5f, 0.5f, 0.5f, 0.5f};

#pragma unroll 1
    for (int c = 0; c < NCHUNK; ++c) {
        __syncthreads();                       // staging of chunk c complete
        if (c + 1 < NCHUNK) stage(c + 1, (c + 1) & 1);
        const _Float16* base = &Ebuf[c & 1][0];
#pragma unroll
        for (int kt = 0; kt < 8; ++kt) {
            half8 a0 = *(const half8*)(base + kt * 1024 + lane * 8);
            half8 a1 = *(const half8*)(base + kt * 1024 + 512 + lane * 8);
#pragma unroll
            for (int r = 0; r < R; ++r) {
                floatx4 acc = __builtin_amdgcn_mfma_f32_16x16x32_f16(a0, zf[r][0], BIAS, 0, 0, 0);
                acc = __builtin_amdgcn_mfma_f32_16x16x32_f16(a1, zf[r][1], acc, 0, 0, 0);
                uint32_t p0 = (__float_as_uint(acc[0]) & 0xFFFFFC00u) | (uint32_t)vki[0];
                uint32_t p1 = (__float_as_uint(acc[1]) & 0xFFFFFC00u) | (uint32_t)vki[1];
                uint32_t p2 = (__float_as_uint(acc[2]) & 0xFFFFFC00u) | (uint32_t)vki[2];
                uint32_t p3 = (__float_as_uint(acc[3]) & 0xFFFFFC00u) | (uint32_t)vki[3];
                // two v_min3-fusable chains
                float t = fminf(fminf(__uint_as_float(p0), __uint_as_float(p1)),
                                __uint_as_float(p2));
                best[r] = fminf(fminf(t, __uint_as_float(p3)), best[r]);
            }
#pragma unroll
            for (int j = 0; j < 4; ++j) vki[j] += 16;
        }
    }

    // cross-lane argmin (packed compare == lexicographic), gather, loss
    float lsum = 0.0f;
#pragma unroll
    for (int r = 0; r < R; ++r) {
        float bv = best[r];
        bv = fminf(bv, __shfl_xor(bv, 16, 64));
        bv = fminf(bv, __shfl_xor(bv, 32, 64));
        const int ki = (int)(__float_as_uint(bv) & 1023u);
        const int row = n0 + r * 16 + lr;
        const float* ep = emb + ((size_t)(g * K + ki)) * C + q * 16;
        const float* zp = z + (size_t)row * GC + g * C + q * 16;
        float*       op = out + (size_t)row * GC + g * C + q * 16;
#pragma unroll
        for (int u = 0; u < 4; ++u) {
            floatx4 e  = *(const floatx4*)(ep + u * 4);
            floatx4 zz = *(const floatx4*)(zp + u * 4);
            *(floatx4*)(op + u * 4) = e;
            floatx4 d = e - zz;
            lsum += d[0] * d[0] + d[1] * d[1] + d[2] * d[2] + d[3] * d[3];
        }
    }
#pragma unroll
    for (int off = 1; off < 64; off <<= 1) lsum += __shfl_xor(lsum, off, 64);
    if (lane == 0) wl[wave] = lsum;
    __syncthreads();
    if (threadIdx.x == 0) {
        float s = (wl[0] + wl[1] + wl[2] + wl[3]) *
                  (1.5f / ((float)NTOK * (float)GC));
        unsafeAtomicAdd(&out[(size_t)NTOK * GC], s);
    }
}

extern "C" void kernel_launch(void* const* d_in, const int* in_sizes, int n_in,
                              void* d_out, int out_size, void* d_ws, size_t ws_size,
                              hipStream_t stream) {
    const float* z   = (const float*)d_in[0];
    const float* emb = (const float*)d_in[1];
    float* out = (float*)d_out;
    _Float16* emb16 = (_Float16*)d_ws;

    vq_prep<<<dim3(128), dim3(256), 0, stream>>>(emb, emb16, out);
    vq_main<<<dim3((NTOK / ROWS_PER_BLOCK) * G), dim3(256), 0, stream>>>(z, emb, emb16, out);
}